// Round 2
// baseline (127.447 us; speedup 1.0000x reference)
//
#include <hip/hip_runtime.h>

// Problem constants (B=2, S=2048, E=1024, H=16, NQ=8, D=64)
#define B_ 2
#define S_ 2048
#define E_ 1024

// out tuple: out [B,S,E] = 4,194,304 floats, attn [B,H,S,S] = 134,217,728 floats
// d_out total = 138,412,032 floats (553.6 MB) -> write-BW bound.

typedef float floatx4 __attribute__((ext_vector_type(4)));  // nontemporal-store-compatible

// ---------------------------------------------------------------------------
// K1: partial column sums of value[b, s, e] over s.  128 splits of 16 rows.
// grid = B*128 = 256 blocks, 256 threads; each thread owns 4 columns (float4).
__global__ void colsum_partial(const float* __restrict__ value,
                               float* __restrict__ part) {
    int bx  = blockIdx.x;          // 0..255
    int b   = bx >> 7;             // batch
    int sp  = bx & 127;            // split
    int tid = threadIdx.x;         // float4 column index 0..255
    const floatx4* v4 = (const floatx4*)value;
    floatx4 acc = (floatx4)0.0f;
    int rowbase = b * S_ + sp * 16;
    #pragma unroll
    for (int r = 0; r < 16; ++r) {
        acc += v4[(size_t)(rowbase + r) * (E_ / 4) + tid];
    }
    ((floatx4*)part)[(size_t)(b * 128 + sp) * (E_ / 4) + tid] = acc;
}

// K2: reduce 128 partials -> vbar[b][e] = mean_s value[b,s,e]
__global__ void finish_vbar(const float* __restrict__ part,
                            float* __restrict__ vbar) {
    int t = blockIdx.x * 256 + threadIdx.x;   // 0..2047
    int b = t >> 10, e = t & 1023;
    float s = 0.f;
    for (int sp = 0; sp < 128; ++sp)
        s += part[(size_t)(b * 128 + sp) * E_ + e];
    vbar[t] = s * (1.0f / (float)S_);
}

// K3/K5: matvec partials: part[b][ks][e] = sum_{k in chunk ks} x[b][k]*W[k][e]
// grid = B*32 = 64 blocks, 256 threads, each thread 4 output columns.
__global__ void mv_partial(const float* __restrict__ x,
                           const float* __restrict__ W,
                           float* __restrict__ part) {
    int bx  = blockIdx.x;          // 0..63
    int b   = bx >> 5, ks = bx & 31;
    int tid = threadIdx.x;
    const floatx4* W4 = (const floatx4*)W;
    floatx4 acc = (floatx4)0.0f;
    int k0 = ks * 32;
    #pragma unroll 8
    for (int kk = 0; kk < 32; ++kk) {
        float s  = x[b * E_ + k0 + kk];
        acc += s * W4[(size_t)(k0 + kk) * (E_ / 4) + tid];
    }
    ((floatx4*)part)[(size_t)(b * 32 + ks) * (E_ / 4) + tid] = acc;
}

// K4/K6: reduce 32 matvec partials + bias -> y[b][e]
__global__ void finish_mv(const float* __restrict__ part,
                          const float* __restrict__ bias,
                          float* __restrict__ y) {
    int t = blockIdx.x * 256 + threadIdx.x;   // 0..2047
    int b = t >> 10, e = t & 1023;
    float s = bias[e];
    for (int sp = 0; sp < 32; ++sp)
        s += part[(size_t)(b * 32 + sp) * E_ + e];
    y[t] = s;
}

// K7: write the whole output. First 4,194,304 floats: broadcast outrow[b][:]
// to every row s. Remaining 134,217,728 floats: constant 1/2048.
__global__ void fill_out(const float* __restrict__ outrow,
                         float* __restrict__ out) {
    const long long OUT0_4 = 1048576;    // B*S*E/4
    const long long TOT4   = 34603008;   // (B*S*E + B*H*S*S)/4
    floatx4* o4 = (floatx4*)out;
    const float A = 1.0f / 2048.0f;      // exact softmax of constant scores
    floatx4 av = (floatx4)A;
    long long stride = (long long)gridDim.x * blockDim.x;
    for (long long i = (long long)blockIdx.x * blockDim.x + threadIdx.x;
         i < TOT4; i += stride) {
        floatx4 w;
        if (i < OUT0_4) {
            int b  = (int)(i >> 19);     // S*E/4 = 2^19
            int e4 = (int)(i & 255);     // E/4 = 256
            w = ((const floatx4*)outrow)[b * 256 + e4];
        } else {
            w = av;
        }
        __builtin_nontemporal_store(w, &o4[i]);
    }
}

extern "C" void kernel_launch(void* const* d_in, const int* in_sizes, int n_in,
                              void* d_out, int out_size, void* d_ws, size_t ws_size,
                              hipStream_t stream) {
    // setup_inputs order: query(0), key(1), value(2), Wq(3), bq(4), Wk(5),
    //                     bk(6), Wv(7), bv(8), Wo(9), bo(10)
    const float* value = (const float*)d_in[2];
    const float* Wv    = (const float*)d_in[7];
    const float* bv    = (const float*)d_in[8];
    const float* Wo    = (const float*)d_in[9];
    const float* bo    = (const float*)d_in[10];
    float* out = (float*)d_out;

    // workspace layout (floats): all offsets 4KB-aligned
    float* ws     = (float*)d_ws;
    float* part1  = ws;                       // 262144 floats (1 MB)
    float* vbar   = part1 + 262144;           // 2048
    float* t1p    = vbar  + 2048;             // 65536 (256 KB)
    float* vbar2  = t1p   + 65536;            // 2048
    float* t2p    = vbar2 + 2048;             // 65536
    float* outrow = t2p   + 65536;            // 2048   (total ~1.6 MB)

    colsum_partial<<<256, 256, 0, stream>>>(value, part1);
    finish_vbar  <<<  8, 256, 0, stream>>>(part1, vbar);
    mv_partial   <<< 64, 256, 0, stream>>>(vbar,  Wv, t1p);
    finish_mv    <<<  8, 256, 0, stream>>>(t1p,   bv, vbar2);
    mv_partial   <<< 64, 256, 0, stream>>>(vbar2, Wo, t2p);
    finish_mv    <<<  8, 256, 0, stream>>>(t2p,   bo, outrow);
    fill_out     <<<2048,256, 0, stream>>>(outrow, out);
}

// Round 3
// 108.955 us; speedup vs baseline: 1.1697x; 1.1697x over previous
//
#include <hip/hip_runtime.h>

// Problem constants (B=2, S=2048, E=1024, H=16, NQ=8, D=64)
// out tuple: out [B,S,E] = 4,194,304 floats, attn [B,H,S,S] = 134,217,728 floats
// d_out = 138,412,032 floats (553.6 MB) -> write-BW bound (~6.8 TB/s achievable).
//
// Strategy: the 537 MB constant attn fill has no dependencies, so it is split
// into 4 chunks co-scheduled with the 4 dependency-chain stages (different
// block roles per kernel) to keep HBM write BW saturated end-to-end.

typedef float floatx4 __attribute__((ext_vector_type(4)));

#define ATTN_BASE4 1048576LL   // B*S*E/4
#define CHUNK4     8388608LL   // (B*H*S*S/4) / 4 chunks
#define FILLB      2048        // fill blocks per kernel (4096 float4 each)

__device__ __forceinline__ void fill_chunk(float* __restrict__ out,
                                           int fb, long long chunk_base) {
    floatx4* o4 = (floatx4*)out;
    const floatx4 av = (floatx4)(1.0f / 2048.0f);  // exact softmax of const scores
    long long base = chunk_base + (long long)fb * 4096 + threadIdx.x;
    #pragma unroll
    for (int it = 0; it < 16; ++it)
        __builtin_nontemporal_store(av, &o4[base + it * 256]);
}

// ---------------------------------------------------------------------------
// K1: blocks 0..255 -> partial column sums of value over s (128 splits x 16
// rows, per batch). blocks 256.. -> fill attn chunk 0.
__global__ void k1_colsum_fill(const float* __restrict__ value,
                               float* __restrict__ part1,
                               float* __restrict__ out) {
    int blk = blockIdx.x;
    if (blk < 256) {
        int b  = blk >> 7, sp = blk & 127, tid = threadIdx.x;
        const floatx4* v4 = (const floatx4*)value;
        floatx4 acc = (floatx4)0.0f;
        int rowbase = b * 2048 + sp * 16;
        #pragma unroll
        for (int r = 0; r < 16; ++r)
            acc += v4[(size_t)(rowbase + r) * 256 + tid];
        ((floatx4*)part1)[(size_t)(b * 128 + sp) * 256 + tid] = acc;
    } else {
        fill_chunk(out, blk - 256, ATTN_BASE4 + 0 * CHUNK4);
    }
}

// ---------------------------------------------------------------------------
// K2: blocks 0..63 -> fused: reduce part1 -> vbar chunk (32 k) -> matvec Wv
// -> t1p partials. blocks 64.. -> fill attn chunk 1.
__global__ void k2_mv1_fill(const float* __restrict__ part1,
                            const float* __restrict__ Wv,
                            float* __restrict__ t1p,
                            float* __restrict__ out) {
    int blk = blockIdx.x;
    if (blk < 64) {
        __shared__ float red[256];
        __shared__ float vbar[32];
        int t = threadIdx.x;
        int b = blk >> 5, ks = blk & 31, k0 = ks * 32;
        int kl = t >> 3, seg = t & 7;
        float s = 0.f;
        #pragma unroll
        for (int i = 0; i < 16; ++i) {
            int sp = seg * 16 + i;
            s += part1[(size_t)(b * 128 + sp) * 1024 + k0 + kl];
        }
        red[t] = s;          // red[kl*8+seg] == red[t]
        __syncthreads();
        if (t < 32) {
            float v = 0.f;
            #pragma unroll
            for (int j = 0; j < 8; ++j) v += red[t * 8 + j];
            vbar[t] = v * (1.0f / 2048.0f);
        }
        __syncthreads();
        const floatx4* W4 = (const floatx4*)Wv;
        floatx4 acc = (floatx4)0.0f;
        #pragma unroll 8
        for (int kk = 0; kk < 32; ++kk)
            acc += vbar[kk] * W4[(size_t)(k0 + kk) * 256 + t];
        ((floatx4*)t1p)[(size_t)(b * 32 + ks) * 256 + t] = acc;
    } else {
        fill_chunk(out, blk - 64, ATTN_BASE4 + 1 * CHUNK4);
    }
}

// ---------------------------------------------------------------------------
// K3: blocks 0..63 -> fused: reduce t1p (+bv) -> vbar2 chunk -> matvec Wo
// -> t2p partials. blocks 64.. -> fill attn chunk 2.
__global__ void k3_mv2_fill(const float* __restrict__ t1p,
                            const float* __restrict__ bv,
                            const float* __restrict__ Wo,
                            float* __restrict__ t2p,
                            float* __restrict__ out) {
    int blk = blockIdx.x;
    if (blk < 64) {
        __shared__ float red[256];
        __shared__ float vbar2[32];
        int t = threadIdx.x;
        int b = blk >> 5, ks = blk & 31, k0 = ks * 32;
        int kl = t >> 3, seg = t & 7;
        float s = 0.f;
        #pragma unroll
        for (int i = 0; i < 4; ++i) {
            int sp = seg * 4 + i;
            s += t1p[(size_t)(b * 32 + sp) * 1024 + k0 + kl];
        }
        red[t] = s;
        __syncthreads();
        if (t < 32) {
            float v = bv[k0 + t];
            #pragma unroll
            for (int j = 0; j < 8; ++j) v += red[t * 8 + j];
            vbar2[t] = v;
        }
        __syncthreads();
        const floatx4* W4 = (const floatx4*)Wo;
        floatx4 acc = (floatx4)0.0f;
        #pragma unroll 8
        for (int kk = 0; kk < 32; ++kk)
            acc += vbar2[kk] * W4[(size_t)(k0 + kk) * 256 + t];
        ((floatx4*)t2p)[(size_t)(b * 32 + ks) * 256 + t] = acc;
    } else {
        fill_chunk(out, blk - 64, ATTN_BASE4 + 2 * CHUNK4);
    }
}

// ---------------------------------------------------------------------------
// K4: blocks 0..63 -> each redundantly reduces t2p (+bo) -> outrow[b] in LDS,
// then broadcasts it to its 64 rows of out. blocks 64.. -> fill attn chunk 3.
__global__ void k4_bcast_fill(const float* __restrict__ t2p,
                              const float* __restrict__ bo,
                              float* __restrict__ out) {
    int blk = blockIdx.x;
    if (blk < 64) {
        __shared__ __align__(16) float orow[1024];
        int t = threadIdx.x;
        int b = blk >> 5, rg = blk & 31;
        int r0 = rg * 64;
        #pragma unroll
        for (int cc = 0; cc < 4; ++cc) {
            int col = cc * 256 + t;
            float s = bo[col];
            for (int sp = 0; sp < 32; ++sp)
                s += t2p[(size_t)(b * 32 + sp) * 1024 + col];
            orow[col] = s;
        }
        __syncthreads();
        floatx4 w = ((const floatx4*)orow)[t];
        floatx4* o4 = (floatx4*)out;
        size_t rowbase = ((size_t)b * 2048 + r0) * 256;  // float4 units
        #pragma unroll 4
        for (int r = 0; r < 64; ++r)
            __builtin_nontemporal_store(w, &o4[rowbase + (size_t)r * 256 + t]);
    } else {
        fill_chunk(out, blk - 64, ATTN_BASE4 + 3 * CHUNK4);
    }
}

extern "C" void kernel_launch(void* const* d_in, const int* in_sizes, int n_in,
                              void* d_out, int out_size, void* d_ws, size_t ws_size,
                              hipStream_t stream) {
    // inputs: query(0) key(1) value(2) Wq(3) bq(4) Wk(5) bk(6) Wv(7) bv(8) Wo(9) bo(10)
    const float* value = (const float*)d_in[2];
    const float* Wv    = (const float*)d_in[7];
    const float* bv    = (const float*)d_in[8];
    const float* Wo    = (const float*)d_in[9];
    const float* bo    = (const float*)d_in[10];
    float* out = (float*)d_out;

    float* ws    = (float*)d_ws;
    float* part1 = ws;              // 262144 floats (1 MB)
    float* t1p   = part1 + 262144;  // 65536 floats (256 KB)
    float* t2p   = t1p   + 65536;   // 65536 floats (256 KB)

    k1_colsum_fill<<<256 + FILLB, 256, 0, stream>>>(value, part1, out);
    k2_mv1_fill   <<< 64 + FILLB, 256, 0, stream>>>(part1, Wv, t1p, out);
    k3_mv2_fill   <<< 64 + FILLB, 256, 0, stream>>>(t1p, bv, Wo, t2p, out);
    k4_bcast_fill <<< 64 + FILLB, 256, 0, stream>>>(t2p, bo, out);
}